// Round 9
// baseline (380.085 us; speedup 1.0000x reference)
//
#include <hip/hip_runtime.h>
#include <stdint.h>

// PointNet EdgeConv, 2 layers. Round 9.
// R4: scalar-pipe weights, atomic-free sort.                   378 us
// R5: packed v_pk_fma_f32.                                     337 us
// R7: algebraic MLP1 elimination (U[src]-V[dst]).              354 us
// R8: MLP2 via v_mfma_f32_32x32x16_bf16.                       331 us
//     -> profile: hist_rank 67 us @ 24 G atomics/s (hard random-atomic rate
//        ceiling), scatter ~50 us of random 8B stores. Sort pipeline dominates.
// R9: atomic-free two-pass bucket sort. All per-edge counting/ranking in LDS;
//     global I/O coalesced (or short contiguous runs). P2 emits row_ptr/cnt
//     directly (bsum/bscan/scan kernels deleted).

#define BS 256
#define K1_EDGES 4096  // edges staged per block in pass 1
#define P2_CAP 3072    // max edges per 128-dst range bucket (mean 2048, +22 sigma)

typedef float v2f __attribute__((ext_vector_type(2)));
typedef __attribute__((ext_vector_type(8))) short bf16x8;
typedef __attribute__((ext_vector_type(16))) float f32x16;

__device__ __forceinline__ unsigned ordenc(float f) {
    unsigned u = __float_as_uint(f);
    return (u & 0x80000000u) ? ~u : (u | 0x80000000u);
}
__device__ __forceinline__ float orddec(unsigned o) {
    unsigned u = (o & 0x80000000u) ? (o ^ 0x80000000u) : ~o;
    return __uint_as_float(u);
}
#define ORD_NEG_INF 0x007FFFFFu  // ordenc(-inf)

__device__ __forceinline__ unsigned pack_bf16_rne(float x, float y) {
    unsigned ux = __float_as_uint(x), uy = __float_as_uint(y);
    ux = ux + 0x7FFFu + ((ux >> 16) & 1u);
    uy = uy + 0x7FFFu + ((uy >> 16) & 1u);
    return (ux >> 16) | (uy & 0xFFFF0000u);
}

// ---------------- utility kernels ----------------

__global__ __launch_bounds__(BS) void init_kernel(unsigned* __restrict__ a,
                                                  unsigned* __restrict__ b, int n32) {
    int i = blockIdx.x * BS + threadIdx.x;
    if (i < n32) {
        a[i] = ORD_NEG_INF;
        b[i] = ORD_NEG_INF;
    }
}

__global__ __launch_bounds__(BS) void finalize_kernel(unsigned* __restrict__ buf, int n) {
    int i = blockIdx.x * BS + threadIdx.x;
    if (i < n) {
        float v = orddec(buf[i]);
        reinterpret_cast<float*>(buf)[i] = fmaxf(v, 0.0f);
    }
}

// ---------------- pass 1a: per-block range histogram (LDS only) -------------
// range r = dst >> 7 (128 dsts per range). NRP <= 1024.
__global__ __launch_bounds__(BS) void bucket_hist_kernel(const int* __restrict__ ei, int E,
                                                         int NRP, int* __restrict__ blockHist) {
    __shared__ int hist[1024];
    const int tid = threadIdx.x;
    for (int r = tid; r < 1024; r += BS) hist[r] = 0;
    __syncthreads();
    const int base = blockIdx.x * K1_EDGES;
    const int M = min(K1_EDGES, E - base);
    for (int i = tid; i < M; i += BS) atomicAdd(&hist[ei[E + base + i] >> 7], 1);
    __syncthreads();
    for (int r = tid; r < NRP; r += BS) blockHist[blockIdx.x * NRP + r] = hist[r];
}

// ---------------- pass 2a: range totals (coalesced column sums) -------------
__global__ __launch_bounds__(BS) void range_total_kernel(const int* __restrict__ blockHist,
                                                         int NB1, int NRP,
                                                         int* __restrict__ total) {
    const int r = blockIdx.x * BS + threadIdx.x;
    if (r >= NRP) return;
    int acc = 0;
    for (int b = 0; b < NB1; ++b) acc += blockHist[b * NRP + r];
    total[r] = acc;
}

// ---------------- pass 2b: exclusive scan of totals -> rangeBase ------------
__global__ __launch_bounds__(1024) void range_scan_kernel(const int* __restrict__ total,
                                                          int NRP, int* __restrict__ rangeBase) {
    __shared__ int s[1024];
    const int t = threadIdx.x;
    const int v = (t < NRP) ? total[t] : 0;
    s[t] = v;
    __syncthreads();
    for (int off = 1; off < 1024; off <<= 1) {
        int add = (t >= off) ? s[t - off] : 0;
        __syncthreads();
        s[t] += add;
        __syncthreads();
    }
    if (t < NRP) rangeBase[t] = s[t] - v;
}

// ---------------- pass 2c: per-(block,range) offsets via wave scans ---------
// off[b][r] = rangeBase[r] + sum_{b'<b} blockHist[b'][r]; one wave per range.
__global__ __launch_bounds__(512) void off_scan_kernel(const int* __restrict__ blockHist,
                                                       int NB1, int NRP,
                                                       const int* __restrict__ rangeBase,
                                                       int* __restrict__ off) {
    const int r = (blockIdx.x * 512 + threadIdx.x) >> 6;
    const int lane = threadIdx.x & 63;
    if (r >= NRP) return;
    int carry = rangeBase[r];
    const int chunks = (NB1 + 63) / 64;
    for (int c = 0; c < chunks; ++c) {
        const int b = c * 64 + lane;
        const int v = (b < NB1) ? blockHist[b * NRP + r] : 0;
        int x = v;
#pragma unroll
        for (int d = 1; d < 64; d <<= 1) {
            int y = __shfl_up(x, d, 64);
            if (lane >= d) x += y;
        }
        if (b < NB1) off[b * NRP + r] = carry + (x - v);
        carry += __shfl(x, 63, 64);
    }
}

// ---------------- pass 1b: LDS-ranked scatter into range buckets ------------
__global__ __launch_bounds__(BS) void bucket_scatter_kernel(const int* __restrict__ ei, int E,
                                                            int NRP, const int* __restrict__ off,
                                                            int2* __restrict__ sedgeB) {
    __shared__ int2 stage[K1_EDGES];            // 32 KB
    __shared__ unsigned short inv[K1_EDGES];    // 8 KB
    __shared__ int hist[1024], start[1024], cursor[1024];
    __shared__ int ts[BS];
    const int tid = threadIdx.x;
    for (int r = tid; r < 1024; r += BS) hist[r] = 0;
    __syncthreads();
    const int base = blockIdx.x * K1_EDGES;
    const int M = min(K1_EDGES, E - base);
    for (int i = tid; i < M; i += BS) {
        const int2 p = make_int2(ei[base + i], ei[E + base + i]);
        stage[i] = p;
        atomicAdd(&hist[p.y >> 7], 1);
    }
    __syncthreads();
    // exclusive scan hist[0..1024) -> start; thread owns 4 contiguous entries
    {
        const int i0 = tid * 4;
        const int l0 = hist[i0], l1 = hist[i0 + 1], l2 = hist[i0 + 2], l3 = hist[i0 + 3];
        const int tsum = l0 + l1 + l2 + l3;
        ts[tid] = tsum;
        __syncthreads();
        for (int off2 = 1; off2 < BS; off2 <<= 1) {
            int add = (tid >= off2) ? ts[tid - off2] : 0;
            __syncthreads();
            ts[tid] += add;
            __syncthreads();
        }
        const int texcl = ts[tid] - tsum;
        start[i0] = texcl;
        start[i0 + 1] = texcl + l0;
        start[i0 + 2] = texcl + l0 + l1;
        start[i0 + 3] = texcl + l0 + l1 + l2;
        cursor[i0] = start[i0];
        cursor[i0 + 1] = start[i0 + 1];
        cursor[i0 + 2] = start[i0 + 2];
        cursor[i0 + 3] = start[i0 + 3];
    }
    __syncthreads();
    for (int i = tid; i < M; i += BS) {
        const int pos = atomicAdd(&cursor[stage[i].y >> 7], 1);
        inv[pos] = (unsigned short)i;
    }
    __syncthreads();
    const int* offb = off + blockIdx.x * NRP;
    for (int j = tid; j < M; j += BS) {
        const int2 p = stage[inv[j]];
        const int r = p.y >> 7;
        sedgeB[offb[r] + (j - start[r])] = p;  // contiguous runs per range
    }
}

// ---------------- pass 3: in-LDS sort within each range bucket --------------
// Also emits row_ptr/cnt for the range's 128 nodes.
__global__ __launch_bounds__(BS) void bucket_sort_kernel(
    const int2* __restrict__ sedgeB, const int* __restrict__ rangeBase,
    const int* __restrict__ total, int N, int2* __restrict__ sedge, int* __restrict__ row_ptr,
    int* __restrict__ cnt) {
    __shared__ int2 stage[P2_CAP];
    __shared__ unsigned short inv[P2_CAP];
    __shared__ int hist[128], start[128], cursor[128];
    const int r = blockIdx.x;
    const int tid = threadIdx.x;
    const int base = rangeBase[r];
    const int M = total[r];
    const bool fast = (M <= P2_CAP);
    if (tid < 128) hist[tid] = 0;
    __syncthreads();
    if (fast) {
        for (int i = tid; i < M; i += BS) {
            const int2 p = sedgeB[base + i];
            stage[i] = p;
            atomicAdd(&hist[p.y & 127], 1);
        }
    } else {  // statistically never (M mean 2048, cap +22 sigma); correct slow path
        if (tid < 128) {
            int c = 0;
            for (int i = 0; i < M; ++i) c += ((sedgeB[base + i].y & 127) == tid);
            hist[tid] = c;
        }
    }
    __syncthreads();
    if (tid < 128) start[tid] = hist[tid];
    __syncthreads();
    for (int off2 = 1; off2 < 128; off2 <<= 1) {
        int add = 0;
        if (tid < 128 && tid >= off2) add = start[tid - off2];
        __syncthreads();
        if (tid < 128) start[tid] += add;
        __syncthreads();
    }
    if (tid < 128) {
        const int excl = start[tid] - hist[tid];
        start[tid] = excl;
        cursor[tid] = excl;
        const int node = r * 128 + tid;
        if (node < N) {
            row_ptr[node] = base + excl;
            cnt[node] = hist[tid];
        }
    }
    __syncthreads();
    if (fast) {
        for (int i = tid; i < M; i += BS) {
            const int pos = atomicAdd(&cursor[stage[i].y & 127], 1);
            inv[pos] = (unsigned short)i;
        }
        __syncthreads();
        for (int j = tid; j < M; j += BS) sedge[base + j] = stage[inv[j]];
    } else {
        if (tid < 128) {
            int c = base + start[tid];
            for (int i = 0; i < M; ++i) {
                const int2 p = sedgeB[base + i];
                if ((p.y & 127) == tid) sedge[c++] = p;
            }
        }
    }
}

// ---------------- per-node U/V precompute ----------------
__global__ __launch_bounds__(BS) void prep1_kernel(const float* __restrict__ pos,
                                                   const float* __restrict__ Wa,
                                                   const float* __restrict__ ba,
                                                   float* __restrict__ U, float* __restrict__ V,
                                                   int N) {
    int n = blockIdx.x * BS + threadIdx.x;
    if (n >= N) return;
    const float p[3] = {pos[3 * n], pos[3 * n + 1], pos[3 * n + 2]};
    v2f u[16], v[16];
#pragma unroll
    for (int g = 0; g < 16; ++g) {
        u[g] = *reinterpret_cast<const v2f*>(&ba[g * 2]);
        v2f z = {0.0f, 0.0f};
        v[g] = z;
    }
#pragma unroll
    for (int i = 0; i < 3; ++i) {
        const v2f f = {p[i], p[i]};
#pragma unroll
        for (int g = 0; g < 16; ++g) {
            const v2f wA = *reinterpret_cast<const v2f*>(&Wa[i * 32 + g * 2]);
            const v2f wB = *reinterpret_cast<const v2f*>(&Wa[(i + 3) * 32 + g * 2]);
            u[g] = __builtin_elementwise_fma(f, wA + wB, u[g]);
            v[g] = __builtin_elementwise_fma(f, wB, v[g]);
        }
    }
    float4* Up = reinterpret_cast<float4*>(U + (size_t)n * 32);
    float4* Vp = reinterpret_cast<float4*>(V + (size_t)n * 32);
#pragma unroll
    for (int q = 0; q < 8; ++q) {
        Up[q] = make_float4(u[2 * q].x, u[2 * q].y, u[2 * q + 1].x, u[2 * q + 1].y);
        Vp[q] = make_float4(v[2 * q].x, v[2 * q].y, v[2 * q + 1].x, v[2 * q + 1].y);
    }
}

__global__ __launch_bounds__(BS) void prep2_kernel(const float* __restrict__ pos,
                                                   const unsigned* __restrict__ aggA,
                                                   const float* __restrict__ Wa,
                                                   const float* __restrict__ ba,
                                                   float* __restrict__ U, float* __restrict__ V,
                                                   int N) {
    int n = blockIdx.x * BS + threadIdx.x;
    if (n >= N) return;
    float h[32];
    const uint4* hp = reinterpret_cast<const uint4*>(aggA + (size_t)n * 32);
#pragma unroll
    for (int q = 0; q < 8; ++q) {
        uint4 t = hp[q];
        h[4 * q + 0] = fmaxf(orddec(t.x), 0.0f);
        h[4 * q + 1] = fmaxf(orddec(t.y), 0.0f);
        h[4 * q + 2] = fmaxf(orddec(t.z), 0.0f);
        h[4 * q + 3] = fmaxf(orddec(t.w), 0.0f);
    }
    const float p[3] = {pos[3 * n], pos[3 * n + 1], pos[3 * n + 2]};
    v2f u[16], v[16];
#pragma unroll
    for (int g = 0; g < 16; ++g) {
        u[g] = *reinterpret_cast<const v2f*>(&ba[g * 2]);
        v2f z = {0.0f, 0.0f};
        v[g] = z;
    }
#pragma unroll
    for (int i = 0; i < 32; ++i) {
        const v2f f = {h[i], h[i]};
#pragma unroll
        for (int g = 0; g < 16; ++g) {
            const v2f w = *reinterpret_cast<const v2f*>(&Wa[i * 32 + g * 2]);
            u[g] = __builtin_elementwise_fma(f, w, u[g]);
        }
    }
#pragma unroll
    for (int i = 0; i < 3; ++i) {
        const v2f f = {p[i], p[i]};
#pragma unroll
        for (int g = 0; g < 16; ++g) {
            const v2f w = *reinterpret_cast<const v2f*>(&Wa[(32 + i) * 32 + g * 2]);
            u[g] = __builtin_elementwise_fma(f, w, u[g]);
            v[g] = __builtin_elementwise_fma(f, w, v[g]);
        }
    }
    float4* Up = reinterpret_cast<float4*>(U + (size_t)n * 32);
    float4* Vp = reinterpret_cast<float4*>(V + (size_t)n * 32);
#pragma unroll
    for (int q = 0; q < 8; ++q) {
        Up[q] = make_float4(u[2 * q].x, u[2 * q].y, u[2 * q + 1].x, u[2 * q + 1].y);
        Vp[q] = make_float4(v[2 * q].x, v[2 * q].y, v[2 * q + 1].x, v[2 * q + 1].y);
    }
}

// ---------------- fused edge kernel: hid -> MFMA MLP2 -> segmented max ------
__global__ __launch_bounds__(BS, 4) void edge_seg_kernel(
    const float4* __restrict__ U, const float4* __restrict__ V,
    const int* __restrict__ row_ptr, const int* __restrict__ cnt,
    const int2* __restrict__ sedge, const float* __restrict__ Wb,
    const float* __restrict__ bb, unsigned* __restrict__ agg, int E) {
    __shared__ __align__(16) unsigned lds[8448];

    const int tid = threadIdx.x;
    const int k0 = blockIdx.x * BS;
    const int blockEnd = min(k0 + BS, E);
    const int k = min(k0 + tid, E - 1);

    // stage Wbt: bf16 pairs, Wbt[n][pair p] = {Wb[2p][n], Wb[2p+1][n]}
    {
        const int n = tid & 31;
        const int p = (tid >> 5) * 2;
        lds[5120 + n * 16 + p + 0] =
            pack_bf16_rne(Wb[(2 * p + 0) * 32 + n], Wb[(2 * p + 1) * 32 + n]);
        lds[5120 + n * 16 + p + 1] =
            pack_bf16_rne(Wb[(2 * p + 2) * 32 + n], Wb[(2 * p + 3) * 32 + n]);
    }

    const int2 ed = sedge[k];
    {
        const float4* Up = U + (size_t)ed.x * 8;
        const float4* Vp = V + (size_t)ed.y * 8;
#pragma unroll
        for (int q = 0; q < 8; ++q) {
            const float4 a = Up[q];
            const float4 b = Vp[q];
            const float h0 = fmaxf(a.x - b.x, 0.0f);
            const float h1 = fmaxf(a.y - b.y, 0.0f);
            const float h2 = fmaxf(a.z - b.z, 0.0f);
            const float h3 = fmaxf(a.w - b.w, 0.0f);
            lds[tid * 20 + 2 * q + 0] = pack_bf16_rne(h0, h1);
            lds[tid * 20 + 2 * q + 1] = pack_bf16_rne(h2, h3);
        }
    }
    __syncthreads();

    const int l = tid & 63;
    const int w = tid >> 6;
    const int half = l >> 5;
    const int ln = l & 31;
    const uint4* ldsv = reinterpret_cast<const uint4*>(lds);

    const int e0 = 64 * w + ln;
    const int e1 = e0 + 32;
    const uint4 au00 = ldsv[e0 * 5 + half];
    const uint4 au01 = ldsv[e0 * 5 + half + 2];
    const uint4 au10 = ldsv[e1 * 5 + half];
    const uint4 au11 = ldsv[e1 * 5 + half + 2];
    const uint4 bu0 = ldsv[1280 + ln * 4 + half];
    const uint4 bu1 = ldsv[1280 + ln * 4 + half + 2];
    const float bbn = bb[ln];
    __syncthreads();

    f32x16 c0 = {};
    f32x16 c1 = {};
    c0 = __builtin_amdgcn_mfma_f32_32x32x16_bf16(__builtin_bit_cast(bf16x8, au00),
                                                 __builtin_bit_cast(bf16x8, bu0), c0, 0, 0, 0);
    c0 = __builtin_amdgcn_mfma_f32_32x32x16_bf16(__builtin_bit_cast(bf16x8, au01),
                                                 __builtin_bit_cast(bf16x8, bu1), c0, 0, 0, 0);
    c1 = __builtin_amdgcn_mfma_f32_32x32x16_bf16(__builtin_bit_cast(bf16x8, au10),
                                                 __builtin_bit_cast(bf16x8, bu0), c1, 0, 0, 0);
    c1 = __builtin_amdgcn_mfma_f32_32x32x16_bf16(__builtin_bit_cast(bf16x8, au11),
                                                 __builtin_bit_cast(bf16x8, bu1), c1, 0, 0, 0);

    float* smf = reinterpret_cast<float*>(lds);
#pragma unroll
    for (int r = 0; r < 16; ++r) {
        const int er = 64 * w + (r & 3) + 8 * (r >> 2) + 4 * half;
        smf[er * 33 + ln] = c0[r] + bbn;
        smf[(er + 32) * 33 + ln] = c1[r] + bbn;
    }
    __syncthreads();

    const int d0 = sedge[k0].y;
    const int d1 = sedge[blockEnd - 1].y;
    const int nPairs = (d1 - d0 + 1) * 32;
    for (int idx = tid; idx < nPairs; idx += BS) {
        const int c = idx & 31;
        const int n = d0 + (idx >> 5);
        const int rs = row_ptr[n];
        const int re = rs + cnt[n];
        const int s0 = max(rs, k0);
        const int s1 = min(re, blockEnd);
        if (s0 >= s1) continue;
        float v0 = -INFINITY, v1 = -INFINITY, v2 = -INFINITY, v3 = -INFINITY;
        int e = s0;
        for (; e + 4 <= s1; e += 4) {
            float a0 = smf[(e - k0 + 0) * 33 + c];
            float a1 = smf[(e - k0 + 1) * 33 + c];
            float a2 = smf[(e - k0 + 2) * 33 + c];
            float a3 = smf[(e - k0 + 3) * 33 + c];
            v0 = fmaxf(v0, a0);
            v1 = fmaxf(v1, a1);
            v2 = fmaxf(v2, a2);
            v3 = fmaxf(v3, a3);
        }
        for (; e < s1; ++e) v0 = fmaxf(v0, smf[(e - k0) * 33 + c]);
        const float v = fmaxf(fmaxf(v0, v1), fmaxf(v2, v3));
        unsigned* p = &agg[(size_t)n * 32 + c];
        const unsigned enc = ordenc(v);
        if (rs >= k0 && re <= blockEnd)
            *p = enc;
        else
            atomicMax(p, enc);
    }
}

extern "C" void kernel_launch(void* const* d_in, const int* in_sizes, int n_in,
                              void* d_out, int out_size, void* d_ws, size_t ws_size,
                              hipStream_t stream) {
    const float* pos = (const float*)d_in[0];
    const int* ei = (const int*)d_in[1];
    const float* W1 = (const float*)d_in[3];
    const float* b1 = (const float*)d_in[4];
    const float* W2 = (const float*)d_in[5];
    const float* b2 = (const float*)d_in[6];
    const float* W3 = (const float*)d_in[7];
    const float* b3 = (const float*)d_in[8];
    const float* W4 = (const float*)d_in[9];
    const float* b4 = (const float*)d_in[10];

    const int E = in_sizes[1] / 2;
    const int N = in_sizes[0] / 3;
    const int n32 = N * 32;
    const int NPAD = ((N + BS - 1) / BS) * BS;
    const int EB = (E + BS - 1) / BS;
    const int NR = (N + 127) / 128;             // ranges of 128 dsts
    const int NRP = ((NR + 15) / 16) * 16;      // padded (<= 1024)
    const int NB1 = (E + K1_EDGES - 1) / K1_EDGES;
    const int BH = NB1 * NRP;                   // blockHist/off elements

    int* cnt = (int*)d_ws;                      // NPAD
    int* row_ptr = cnt + NPAD;                  // NPAD
    int* blockHist = row_ptr + NPAD;            // BH
    int* off = blockHist + BH;                  // BH
    int* total = off + BH;                      // NRP
    int* rangeBase = total + NRP;               // NRP
    int2* sedge = (int2*)(rangeBase + NRP);     // E  (offsets all mult-of-4 ints)
    unsigned* aggA = (unsigned*)(sedge + E);    // n32 (ord-encoded; prep2 decodes)
    float* Ubuf = (float*)(aggA + n32);         // n32
    float* Vbuf = Ubuf + n32;                   // n32
    int2* sedgeB = (int2*)Ubuf;  // aliases Ubuf: dead before prep1 writes U
    unsigned* aggB = (unsigned*)d_out;

    const int gridN32 = (n32 + BS - 1) / BS;
    const int NBn = (N + BS - 1) / BS;

    init_kernel<<<gridN32, BS, 0, stream>>>(aggA, aggB, n32);

    // --- atomic-free bucket sort -> sedge, row_ptr, cnt ---
    bucket_hist_kernel<<<NB1, BS, 0, stream>>>(ei, E, NRP, blockHist);
    range_total_kernel<<<(NRP + BS - 1) / BS, BS, 0, stream>>>(blockHist, NB1, NRP, total);
    range_scan_kernel<<<1, 1024, 0, stream>>>(total, NRP, rangeBase);
    off_scan_kernel<<<(NRP * 64 + 511) / 512, 512, 0, stream>>>(blockHist, NB1, NRP, rangeBase,
                                                                off);
    bucket_scatter_kernel<<<NB1, BS, 0, stream>>>(ei, E, NRP, off, sedgeB);
    bucket_sort_kernel<<<NR, BS, 0, stream>>>(sedgeB, rangeBase, total, N, sedge, row_ptr, cnt);

    // --- layer 1 ---
    prep1_kernel<<<NBn, BS, 0, stream>>>(pos, W1, b1, Ubuf, Vbuf, N);
    edge_seg_kernel<<<EB, BS, 0, stream>>>((const float4*)Ubuf, (const float4*)Vbuf, row_ptr,
                                           cnt, sedge, W2, b2, aggA, E);
    // --- layer 2 ---
    prep2_kernel<<<NBn, BS, 0, stream>>>(pos, aggA, W3, b3, Ubuf, Vbuf, N);
    edge_seg_kernel<<<EB, BS, 0, stream>>>((const float4*)Ubuf, (const float4*)Vbuf, row_ptr,
                                           cnt, sedge, W4, b4, aggB, E);
    finalize_kernel<<<gridN32, BS, 0, stream>>>(aggB, n32);
}

// Round 10
// 278.384 us; speedup vs baseline: 1.3653x; 1.3653x over previous
//
#include <hip/hip_runtime.h>
#include <stdint.h>

// PointNet EdgeConv, 2 layers. Round 10.
// R5: packed v_pk_fma_f32.                                     337 us
// R7: algebraic MLP1 elimination (U[src]-V[dst]).              354 us
// R8: MLP2 via v_mfma_f32_32x32x16_bf16.                       331 us
// R9: atomic-free bucket sort, BUT range_total_kernel was 1-thread-per-range
//     (784 threads total, 101 us latency-bound). REGRESSED.    380 us
// R10: range_total deleted — off_scan's wave-scan final carry IS the total.
//      Order: hist -> off_scan(local prefix + totals) -> range_scan(base)
//      -> scatter(base+off at use) -> bucket_sort. Compute path unchanged.

#define BS 256
#define K1_EDGES 4096  // edges staged per block in pass 1
#define P2_CAP 3072    // max edges per 128-dst range bucket (mean 2048, +22 sigma)

typedef float v2f __attribute__((ext_vector_type(2)));
typedef __attribute__((ext_vector_type(8))) short bf16x8;
typedef __attribute__((ext_vector_type(16))) float f32x16;

__device__ __forceinline__ unsigned ordenc(float f) {
    unsigned u = __float_as_uint(f);
    return (u & 0x80000000u) ? ~u : (u | 0x80000000u);
}
__device__ __forceinline__ float orddec(unsigned o) {
    unsigned u = (o & 0x80000000u) ? (o ^ 0x80000000u) : ~o;
    return __uint_as_float(u);
}
#define ORD_NEG_INF 0x007FFFFFu  // ordenc(-inf)

__device__ __forceinline__ unsigned pack_bf16_rne(float x, float y) {
    unsigned ux = __float_as_uint(x), uy = __float_as_uint(y);
    ux = ux + 0x7FFFu + ((ux >> 16) & 1u);
    uy = uy + 0x7FFFu + ((uy >> 16) & 1u);
    return (ux >> 16) | (uy & 0xFFFF0000u);
}

// ---------------- utility kernels ----------------

__global__ __launch_bounds__(BS) void init_kernel(unsigned* __restrict__ a,
                                                  unsigned* __restrict__ b, int n32) {
    int i = blockIdx.x * BS + threadIdx.x;
    if (i < n32) {
        a[i] = ORD_NEG_INF;
        b[i] = ORD_NEG_INF;
    }
}

__global__ __launch_bounds__(BS) void finalize_kernel(unsigned* __restrict__ buf, int n) {
    int i = blockIdx.x * BS + threadIdx.x;
    if (i < n) {
        float v = orddec(buf[i]);
        reinterpret_cast<float*>(buf)[i] = fmaxf(v, 0.0f);
    }
}

// ---------------- pass 1a: per-block range histogram (LDS only) -------------
// range r = dst >> 7 (128 dsts per range). NRP <= 1024.
__global__ __launch_bounds__(BS) void bucket_hist_kernel(const int* __restrict__ ei, int E,
                                                         int NRP, int* __restrict__ blockHist) {
    __shared__ int hist[1024];
    const int tid = threadIdx.x;
    for (int r = tid; r < 1024; r += BS) hist[r] = 0;
    __syncthreads();
    const int base = blockIdx.x * K1_EDGES;
    const int M = min(K1_EDGES, E - base);
    for (int i = tid; i < M; i += BS) atomicAdd(&hist[ei[E + base + i] >> 7], 1);
    __syncthreads();
    for (int r = tid; r < NRP; r += BS) blockHist[blockIdx.x * NRP + r] = hist[r];
}

// ---------------- pass 2a: per-(block,range) LOCAL prefixes + range totals --
// One wave per range: off[b][r] = sum_{b'<b} blockHist[b'][r]; total[r] = sum.
__global__ __launch_bounds__(512) void off_scan_kernel(const int* __restrict__ blockHist,
                                                       int NB1, int NRP,
                                                       int* __restrict__ off,
                                                       int* __restrict__ total) {
    const int r = (blockIdx.x * 512 + threadIdx.x) >> 6;
    const int lane = threadIdx.x & 63;
    if (r >= NRP) return;
    int carry = 0;
    const int chunks = (NB1 + 63) / 64;
    for (int c = 0; c < chunks; ++c) {
        const int b = c * 64 + lane;
        const int v = (b < NB1) ? blockHist[b * NRP + r] : 0;
        int x = v;
#pragma unroll
        for (int d = 1; d < 64; d <<= 1) {
            int y = __shfl_up(x, d, 64);
            if (lane >= d) x += y;
        }
        if (b < NB1) off[b * NRP + r] = carry + (x - v);
        carry += __shfl(x, 63, 64);  // uniform across lanes
    }
    if (lane == 0) total[r] = carry;
}

// ---------------- pass 2b: exclusive scan of totals -> rangeBase ------------
__global__ __launch_bounds__(1024) void range_scan_kernel(const int* __restrict__ total,
                                                          int NRP, int* __restrict__ rangeBase) {
    __shared__ int s[1024];
    const int t = threadIdx.x;
    const int v = (t < NRP) ? total[t] : 0;
    s[t] = v;
    __syncthreads();
    for (int off = 1; off < 1024; off <<= 1) {
        int add = (t >= off) ? s[t - off] : 0;
        __syncthreads();
        s[t] += add;
        __syncthreads();
    }
    if (t < NRP) rangeBase[t] = s[t] - v;
}

// ---------------- pass 1b: LDS-ranked scatter into range buckets ------------
__global__ __launch_bounds__(BS) void bucket_scatter_kernel(
    const int* __restrict__ ei, int E, int NRP, const int* __restrict__ off,
    const int* __restrict__ rangeBase, int2* __restrict__ sedgeB) {
    __shared__ int2 stage[K1_EDGES];          // 32 KB
    __shared__ unsigned short inv[K1_EDGES];  // 8 KB
    __shared__ int hist[1024], start[1024], cursor[1024];
    __shared__ int ts[BS];
    const int tid = threadIdx.x;
    for (int r = tid; r < 1024; r += BS) hist[r] = 0;
    __syncthreads();
    const int base = blockIdx.x * K1_EDGES;
    const int M = min(K1_EDGES, E - base);
    for (int i = tid; i < M; i += BS) {
        const int2 p = make_int2(ei[base + i], ei[E + base + i]);
        stage[i] = p;
        atomicAdd(&hist[p.y >> 7], 1);
    }
    __syncthreads();
    // exclusive scan hist[0..1024) -> start; thread owns 4 contiguous entries
    {
        const int i0 = tid * 4;
        const int l0 = hist[i0], l1 = hist[i0 + 1], l2 = hist[i0 + 2], l3 = hist[i0 + 3];
        const int tsum = l0 + l1 + l2 + l3;
        ts[tid] = tsum;
        __syncthreads();
        for (int off2 = 1; off2 < BS; off2 <<= 1) {
            int add = (tid >= off2) ? ts[tid - off2] : 0;
            __syncthreads();
            ts[tid] += add;
            __syncthreads();
        }
        const int texcl = ts[tid] - tsum;
        start[i0] = texcl;
        start[i0 + 1] = texcl + l0;
        start[i0 + 2] = texcl + l0 + l1;
        start[i0 + 3] = texcl + l0 + l1 + l2;
        cursor[i0] = start[i0];
        cursor[i0 + 1] = start[i0 + 1];
        cursor[i0 + 2] = start[i0 + 2];
        cursor[i0 + 3] = start[i0 + 3];
    }
    __syncthreads();
    for (int i = tid; i < M; i += BS) {
        const int pos = atomicAdd(&cursor[stage[i].y >> 7], 1);
        inv[pos] = (unsigned short)i;
    }
    __syncthreads();
    const int* offb = off + blockIdx.x * NRP;
    for (int j = tid; j < M; j += BS) {
        const int2 p = stage[inv[j]];
        const int r = p.y >> 7;
        sedgeB[rangeBase[r] + offb[r] + (j - start[r])] = p;  // contiguous runs
    }
}

// ---------------- pass 3: in-LDS sort within each range bucket --------------
// Also emits row_ptr/cnt for the range's 128 nodes.
__global__ __launch_bounds__(BS) void bucket_sort_kernel(
    const int2* __restrict__ sedgeB, const int* __restrict__ rangeBase,
    const int* __restrict__ total, int N, int2* __restrict__ sedge, int* __restrict__ row_ptr,
    int* __restrict__ cnt) {
    __shared__ int2 stage[P2_CAP];
    __shared__ unsigned short inv[P2_CAP];
    __shared__ int hist[128], start[128], cursor[128];
    const int r = blockIdx.x;
    const int tid = threadIdx.x;
    const int base = rangeBase[r];
    const int M = total[r];
    const bool fast = (M <= P2_CAP);
    if (tid < 128) hist[tid] = 0;
    __syncthreads();
    if (fast) {
        for (int i = tid; i < M; i += BS) {
            const int2 p = sedgeB[base + i];
            stage[i] = p;
            atomicAdd(&hist[p.y & 127], 1);
        }
    } else {  // statistically never; correct slow path
        if (tid < 128) {
            int c = 0;
            for (int i = 0; i < M; ++i) c += ((sedgeB[base + i].y & 127) == tid);
            hist[tid] = c;
        }
    }
    __syncthreads();
    if (tid < 128) start[tid] = hist[tid];
    __syncthreads();
    for (int off2 = 1; off2 < 128; off2 <<= 1) {
        int add = 0;
        if (tid < 128 && tid >= off2) add = start[tid - off2];
        __syncthreads();
        if (tid < 128) start[tid] += add;
        __syncthreads();
    }
    if (tid < 128) {
        const int excl = start[tid] - hist[tid];
        start[tid] = excl;
        cursor[tid] = excl;
        const int node = r * 128 + tid;
        if (node < N) {
            row_ptr[node] = base + excl;
            cnt[node] = hist[tid];
        }
    }
    __syncthreads();
    if (fast) {
        for (int i = tid; i < M; i += BS) {
            const int pos = atomicAdd(&cursor[stage[i].y & 127], 1);
            inv[pos] = (unsigned short)i;
        }
        __syncthreads();
        for (int j = tid; j < M; j += BS) sedge[base + j] = stage[inv[j]];
    } else {
        if (tid < 128) {
            int c = base + start[tid];
            for (int i = 0; i < M; ++i) {
                const int2 p = sedgeB[base + i];
                if ((p.y & 127) == tid) sedge[c++] = p;
            }
        }
    }
}

// ---------------- per-node U/V precompute ----------------
__global__ __launch_bounds__(BS) void prep1_kernel(const float* __restrict__ pos,
                                                   const float* __restrict__ Wa,
                                                   const float* __restrict__ ba,
                                                   float* __restrict__ U, float* __restrict__ V,
                                                   int N) {
    int n = blockIdx.x * BS + threadIdx.x;
    if (n >= N) return;
    const float p[3] = {pos[3 * n], pos[3 * n + 1], pos[3 * n + 2]};
    v2f u[16], v[16];
#pragma unroll
    for (int g = 0; g < 16; ++g) {
        u[g] = *reinterpret_cast<const v2f*>(&ba[g * 2]);
        v2f z = {0.0f, 0.0f};
        v[g] = z;
    }
#pragma unroll
    for (int i = 0; i < 3; ++i) {
        const v2f f = {p[i], p[i]};
#pragma unroll
        for (int g = 0; g < 16; ++g) {
            const v2f wA = *reinterpret_cast<const v2f*>(&Wa[i * 32 + g * 2]);
            const v2f wB = *reinterpret_cast<const v2f*>(&Wa[(i + 3) * 32 + g * 2]);
            u[g] = __builtin_elementwise_fma(f, wA + wB, u[g]);
            v[g] = __builtin_elementwise_fma(f, wB, v[g]);
        }
    }
    float4* Up = reinterpret_cast<float4*>(U + (size_t)n * 32);
    float4* Vp = reinterpret_cast<float4*>(V + (size_t)n * 32);
#pragma unroll
    for (int q = 0; q < 8; ++q) {
        Up[q] = make_float4(u[2 * q].x, u[2 * q].y, u[2 * q + 1].x, u[2 * q + 1].y);
        Vp[q] = make_float4(v[2 * q].x, v[2 * q].y, v[2 * q + 1].x, v[2 * q + 1].y);
    }
}

__global__ __launch_bounds__(BS) void prep2_kernel(const float* __restrict__ pos,
                                                   const unsigned* __restrict__ aggA,
                                                   const float* __restrict__ Wa,
                                                   const float* __restrict__ ba,
                                                   float* __restrict__ U, float* __restrict__ V,
                                                   int N) {
    int n = blockIdx.x * BS + threadIdx.x;
    if (n >= N) return;
    float h[32];
    const uint4* hp = reinterpret_cast<const uint4*>(aggA + (size_t)n * 32);
#pragma unroll
    for (int q = 0; q < 8; ++q) {
        uint4 t = hp[q];
        h[4 * q + 0] = fmaxf(orddec(t.x), 0.0f);
        h[4 * q + 1] = fmaxf(orddec(t.y), 0.0f);
        h[4 * q + 2] = fmaxf(orddec(t.z), 0.0f);
        h[4 * q + 3] = fmaxf(orddec(t.w), 0.0f);
    }
    const float p[3] = {pos[3 * n], pos[3 * n + 1], pos[3 * n + 2]};
    v2f u[16], v[16];
#pragma unroll
    for (int g = 0; g < 16; ++g) {
        u[g] = *reinterpret_cast<const v2f*>(&ba[g * 2]);
        v2f z = {0.0f, 0.0f};
        v[g] = z;
    }
#pragma unroll
    for (int i = 0; i < 32; ++i) {
        const v2f f = {h[i], h[i]};
#pragma unroll
        for (int g = 0; g < 16; ++g) {
            const v2f w = *reinterpret_cast<const v2f*>(&Wa[i * 32 + g * 2]);
            u[g] = __builtin_elementwise_fma(f, w, u[g]);
        }
    }
#pragma unroll
    for (int i = 0; i < 3; ++i) {
        const v2f f = {p[i], p[i]};
#pragma unroll
        for (int g = 0; g < 16; ++g) {
            const v2f w = *reinterpret_cast<const v2f*>(&Wa[(32 + i) * 32 + g * 2]);
            u[g] = __builtin_elementwise_fma(f, w, u[g]);
            v[g] = __builtin_elementwise_fma(f, w, v[g]);
        }
    }
    float4* Up = reinterpret_cast<float4*>(U + (size_t)n * 32);
    float4* Vp = reinterpret_cast<float4*>(V + (size_t)n * 32);
#pragma unroll
    for (int q = 0; q < 8; ++q) {
        Up[q] = make_float4(u[2 * q].x, u[2 * q].y, u[2 * q + 1].x, u[2 * q + 1].y);
        Vp[q] = make_float4(v[2 * q].x, v[2 * q].y, v[2 * q + 1].x, v[2 * q + 1].y);
    }
}

// ---------------- fused edge kernel: hid -> MFMA MLP2 -> segmented max ------
__global__ __launch_bounds__(BS, 4) void edge_seg_kernel(
    const float4* __restrict__ U, const float4* __restrict__ V,
    const int* __restrict__ row_ptr, const int* __restrict__ cnt,
    const int2* __restrict__ sedge, const float* __restrict__ Wb,
    const float* __restrict__ bb, unsigned* __restrict__ agg, int E) {
    __shared__ __align__(16) unsigned lds[8448];

    const int tid = threadIdx.x;
    const int k0 = blockIdx.x * BS;
    const int blockEnd = min(k0 + BS, E);
    const int k = min(k0 + tid, E - 1);

    // stage Wbt: bf16 pairs, Wbt[n][pair p] = {Wb[2p][n], Wb[2p+1][n]}
    {
        const int n = tid & 31;
        const int p = (tid >> 5) * 2;
        lds[5120 + n * 16 + p + 0] =
            pack_bf16_rne(Wb[(2 * p + 0) * 32 + n], Wb[(2 * p + 1) * 32 + n]);
        lds[5120 + n * 16 + p + 1] =
            pack_bf16_rne(Wb[(2 * p + 2) * 32 + n], Wb[(2 * p + 3) * 32 + n]);
    }

    const int2 ed = sedge[k];
    {
        const float4* Up = U + (size_t)ed.x * 8;
        const float4* Vp = V + (size_t)ed.y * 8;
#pragma unroll
        for (int q = 0; q < 8; ++q) {
            const float4 a = Up[q];
            const float4 b = Vp[q];
            const float h0 = fmaxf(a.x - b.x, 0.0f);
            const float h1 = fmaxf(a.y - b.y, 0.0f);
            const float h2 = fmaxf(a.z - b.z, 0.0f);
            const float h3 = fmaxf(a.w - b.w, 0.0f);
            lds[tid * 20 + 2 * q + 0] = pack_bf16_rne(h0, h1);
            lds[tid * 20 + 2 * q + 1] = pack_bf16_rne(h2, h3);
        }
    }
    __syncthreads();

    const int l = tid & 63;
    const int w = tid >> 6;
    const int half = l >> 5;
    const int ln = l & 31;
    const uint4* ldsv = reinterpret_cast<const uint4*>(lds);

    const int e0 = 64 * w + ln;
    const int e1 = e0 + 32;
    const uint4 au00 = ldsv[e0 * 5 + half];
    const uint4 au01 = ldsv[e0 * 5 + half + 2];
    const uint4 au10 = ldsv[e1 * 5 + half];
    const uint4 au11 = ldsv[e1 * 5 + half + 2];
    const uint4 bu0 = ldsv[1280 + ln * 4 + half];
    const uint4 bu1 = ldsv[1280 + ln * 4 + half + 2];
    const float bbn = bb[ln];
    __syncthreads();

    f32x16 c0 = {};
    f32x16 c1 = {};
    c0 = __builtin_amdgcn_mfma_f32_32x32x16_bf16(__builtin_bit_cast(bf16x8, au00),
                                                 __builtin_bit_cast(bf16x8, bu0), c0, 0, 0, 0);
    c0 = __builtin_amdgcn_mfma_f32_32x32x16_bf16(__builtin_bit_cast(bf16x8, au01),
                                                 __builtin_bit_cast(bf16x8, bu1), c0, 0, 0, 0);
    c1 = __builtin_amdgcn_mfma_f32_32x32x16_bf16(__builtin_bit_cast(bf16x8, au10),
                                                 __builtin_bit_cast(bf16x8, bu0), c1, 0, 0, 0);
    c1 = __builtin_amdgcn_mfma_f32_32x32x16_bf16(__builtin_bit_cast(bf16x8, au11),
                                                 __builtin_bit_cast(bf16x8, bu1), c1, 0, 0, 0);

    float* smf = reinterpret_cast<float*>(lds);
#pragma unroll
    for (int r = 0; r < 16; ++r) {
        const int er = 64 * w + (r & 3) + 8 * (r >> 2) + 4 * half;
        smf[er * 33 + ln] = c0[r] + bbn;
        smf[(er + 32) * 33 + ln] = c1[r] + bbn;
    }
    __syncthreads();

    const int d0 = sedge[k0].y;
    const int d1 = sedge[blockEnd - 1].y;
    const int nPairs = (d1 - d0 + 1) * 32;
    for (int idx = tid; idx < nPairs; idx += BS) {
        const int c = idx & 31;
        const int n = d0 + (idx >> 5);
        const int rs = row_ptr[n];
        const int re = rs + cnt[n];
        const int s0 = max(rs, k0);
        const int s1 = min(re, blockEnd);
        if (s0 >= s1) continue;
        float v0 = -INFINITY, v1 = -INFINITY, v2 = -INFINITY, v3 = -INFINITY;
        int e = s0;
        for (; e + 4 <= s1; e += 4) {
            float a0 = smf[(e - k0 + 0) * 33 + c];
            float a1 = smf[(e - k0 + 1) * 33 + c];
            float a2 = smf[(e - k0 + 2) * 33 + c];
            float a3 = smf[(e - k0 + 3) * 33 + c];
            v0 = fmaxf(v0, a0);
            v1 = fmaxf(v1, a1);
            v2 = fmaxf(v2, a2);
            v3 = fmaxf(v3, a3);
        }
        for (; e < s1; ++e) v0 = fmaxf(v0, smf[(e - k0) * 33 + c]);
        const float v = fmaxf(fmaxf(v0, v1), fmaxf(v2, v3));
        unsigned* p = &agg[(size_t)n * 32 + c];
        const unsigned enc = ordenc(v);
        if (rs >= k0 && re <= blockEnd)
            *p = enc;
        else
            atomicMax(p, enc);
    }
}

extern "C" void kernel_launch(void* const* d_in, const int* in_sizes, int n_in,
                              void* d_out, int out_size, void* d_ws, size_t ws_size,
                              hipStream_t stream) {
    const float* pos = (const float*)d_in[0];
    const int* ei = (const int*)d_in[1];
    const float* W1 = (const float*)d_in[3];
    const float* b1 = (const float*)d_in[4];
    const float* W2 = (const float*)d_in[5];
    const float* b2 = (const float*)d_in[6];
    const float* W3 = (const float*)d_in[7];
    const float* b3 = (const float*)d_in[8];
    const float* W4 = (const float*)d_in[9];
    const float* b4 = (const float*)d_in[10];

    const int E = in_sizes[1] / 2;
    const int N = in_sizes[0] / 3;
    const int n32 = N * 32;
    const int NPAD = ((N + BS - 1) / BS) * BS;
    const int EB = (E + BS - 1) / BS;
    const int NR = (N + 127) / 128;         // ranges of 128 dsts
    const int NRP = ((NR + 15) / 16) * 16;  // padded (<= 1024)
    const int NB1 = (E + K1_EDGES - 1) / K1_EDGES;
    const int BH = NB1 * NRP;

    int* cnt = (int*)d_ws;                    // NPAD
    int* row_ptr = cnt + NPAD;                // NPAD
    int* blockHist = row_ptr + NPAD;          // BH
    int* off = blockHist + BH;                // BH
    int* total = off + BH;                    // NRP
    int* rangeBase = total + NRP;             // NRP
    int2* sedge = (int2*)(rangeBase + NRP);   // E (offsets all mult-of-4 ints)
    unsigned* aggA = (unsigned*)(sedge + E);  // n32 (ord-encoded; prep2 decodes)
    float* Ubuf = (float*)(aggA + n32);       // n32
    float* Vbuf = Ubuf + n32;                 // n32
    int2* sedgeB = (int2*)Ubuf;               // aliases Ubuf (dead before prep1)
    unsigned* aggB = (unsigned*)d_out;

    const int gridN32 = (n32 + BS - 1) / BS;
    const int NBn = (N + BS - 1) / BS;

    init_kernel<<<gridN32, BS, 0, stream>>>(aggA, aggB, n32);

    // --- atomic-free bucket sort -> sedge, row_ptr, cnt ---
    bucket_hist_kernel<<<NB1, BS, 0, stream>>>(ei, E, NRP, blockHist);
    off_scan_kernel<<<(NRP * 64 + 511) / 512, 512, 0, stream>>>(blockHist, NB1, NRP, off,
                                                                total);
    range_scan_kernel<<<1, 1024, 0, stream>>>(total, NRP, rangeBase);
    bucket_scatter_kernel<<<NB1, BS, 0, stream>>>(ei, E, NRP, off, rangeBase, sedgeB);
    bucket_sort_kernel<<<NR, BS, 0, stream>>>(sedgeB, rangeBase, total, N, sedge, row_ptr, cnt);

    // --- layer 1 ---
    prep1_kernel<<<NBn, BS, 0, stream>>>(pos, W1, b1, Ubuf, Vbuf, N);
    edge_seg_kernel<<<EB, BS, 0, stream>>>((const float4*)Ubuf, (const float4*)Vbuf, row_ptr,
                                           cnt, sedge, W2, b2, aggA, E);
    // --- layer 2 ---
    prep2_kernel<<<NBn, BS, 0, stream>>>(pos, aggA, W3, b3, Ubuf, Vbuf, N);
    edge_seg_kernel<<<EB, BS, 0, stream>>>((const float4*)Ubuf, (const float4*)Vbuf, row_ptr,
                                           cnt, sedge, W4, b4, aggB, E);
    finalize_kernel<<<gridN32, BS, 0, stream>>>(aggB, n32);
}